// Round 3
// baseline (90.751 us; speedup 1.0000x reference)
//
#include <hip/hip_runtime.h>

typedef __attribute__((ext_vector_type(4))) float f32x4;
typedef __attribute__((ext_vector_type(8))) short bf16x8;

#define NP 4096
#define GC 16                 // sort grid GC x GC
#define NCELLS (GC * GC)      // 256
#define IB 4                  // sorted peds per pool block

__device__ __forceinline__ unsigned short f2bf(float f) {
  unsigned int u = __float_as_uint(f);
  u = u + 0x7FFFu + ((u >> 16) & 1u);   // round-to-nearest-even
  return (unsigned short)(u >> 16);
}

__global__ __launch_bounds__(256) void prep_kernel(
    const float2* __restrict__ pos, const float2* __restrict__ past,
    float4* __restrict__ posvel, int* __restrict__ cellid) {
  int i = blockIdx.x * 256 + threadIdx.x;
  float2 p = pos[i];
  float2 q = past[i];
  posvel[i] = make_float4(p.x, p.y, p.x - q.x, p.y - q.y);
  int cx = (int)(p.x * (GC / 20.0f));
  int cy = (int)(p.y * (GC / 20.0f));
  cx = min(max(cx, 0), GC - 1);
  cy = min(max(cy, 0), GC - 1);
  cellid[i] = cx * GC + cy;
}

// Counting sort by coarse cell: single block, 256 threads.
__global__ __launch_bounds__(256) void sort_kernel(
    const float4* __restrict__ posvel, const int* __restrict__ cellid,
    float4* __restrict__ sorted, int* __restrict__ orig) {
  __shared__ int hist[NCELLS];
  __shared__ int scan[NCELLS];
  const int tid = threadIdx.x;
  hist[tid] = 0;
  __syncthreads();
  for (int p = tid; p < NP; p += 256) atomicAdd(&hist[cellid[p]], 1);
  __syncthreads();
  scan[tid] = hist[tid];
  __syncthreads();
  for (int off = 1; off < NCELLS; off <<= 1) {
    int u = (tid >= off) ? scan[tid - off] : 0;
    __syncthreads();
    scan[tid] += u;
    __syncthreads();
  }
  // exclusive start -> reuse hist as cursor
  hist[tid] = scan[tid] - hist[tid];
  __syncthreads();
  for (int p = tid; p < NP; p += 256) {
    int c = cellid[p];
    int dst = atomicAdd(&hist[c], 1);
    sorted[dst] = posvel[p];
    orig[dst] = p;
  }
}

// Block = IB sorted (spatially adjacent) peds, 8 waves: wave w -> i_local=w>>1,
// half sub=w&1. Each wave sweeps 64-j chunks; sorted order makes the in-range
// predicate wave-coherent so far chunks skip the IEEE-div path entirely.
// Self-pair lands in cell 136 with vals (0,0), cnt 1; compensated in epilogue.
__global__ __launch_bounds__(512, 8) void pool_kernel(
    const float4* __restrict__ sorted, const int* __restrict__ orig,
    unsigned short* __restrict__ gridws) {
  __shared__ float acc[IB][NCELLS * 3];
  const int tid = threadIdx.x;
  const int lane = tid & 63;
  const int w = tid >> 6;
  const int il = w >> 1;
  const int sub = w & 1;
  const int isrt = blockIdx.x * IB + il;

  for (int idx = tid; idx < IB * NCELLS * 3; idx += 512)
    ((float*)acc)[idx] = 0.0f;
  __syncthreads();

  const float4 pvi = sorted[isrt];
  float* grid = acc[il];
  const float inv06 = 1.0f / 0.6f;

  auto process = [&](float4 pvj) {
    float rx = pvj.x - pvi.x;
    float ry = pvj.y - pvi.y;
    float tx = __builtin_fmaf(rx, inv06, 8.0f);   // approx, prefilter only
    float ty = __builtin_fmaf(ry, inv06, 8.0f);
    bool near = (tx > -0.01f) & (tx < 16.01f) & (ty > -0.01f) & (ty < 16.01f);
    if (__any(near)) {
      // exact IEEE fp32 division to match numpy floor(rel/0.6 + 8)
      float fx = floorf(rx / 0.6f + 8.0f);
      float fy = floorf(ry / 0.6f + 8.0f);
      int ix = (int)fx;
      int iy = (int)fy;
      if (((unsigned)ix < 16u) & ((unsigned)iy < 16u)) {
        float* p = &grid[((ix << 4) + iy) * 3];
        atomicAdd(p + 0, pvj.z - pvi.z);
        atomicAdd(p + 1, pvj.w - pvi.w);
        atomicAdd(p + 2, 1.0f);
      }
    }
  };

  for (int jo = 0; jo < NP; jo += 256) {
    float4 a = sorted[jo + sub * 64 + lane];
    float4 b = sorted[jo + 128 + sub * 64 + lane];
    process(a);
    process(b);
  }
  __syncthreads();

  // epilogue: normalize and store bf16 grid rows at ORIGINAL ped index
  const int cell = tid & (NCELLS - 1);
  const int half = tid >> 8;  // 0: il 0-1, 1: il 2-3
  const float selfc = (cell == 136) ? 1.0f : 0.0f;
#pragma unroll
  for (int k = 0; k < 2; ++k) {
    int il2 = half * 2 + k;
    int io = orig[blockIdx.x * IB + il2];
    float sx = acc[il2][cell * 3 + 0];
    float sy = acc[il2][cell * 3 + 1];
    float cn = acc[il2][cell * 3 + 2] - selfc;
    float d = fmaxf(cn, 1.0f);
    unsigned int packed =
        ((unsigned int)f2bf(sy / d) << 16) | (unsigned int)f2bf(sx / d);
    *(unsigned int*)&gridws[(size_t)io * 512 + cell * 2] = packed;
  }
}

// C[4096][256] = relu(A[4096][512](bf16) * W[256][512]^T + b), fp32 out.
// 64x64 tile per block, 4 waves in 2x2 quadrants, each wave 2x2 MFMA frags.
// LDS rows padded to 40 ushorts (80B): ds_read_b128 2-way conflict (free).
__global__ __launch_bounds__(256) void gemm_kernel(
    const unsigned short* __restrict__ A, const float* __restrict__ W,
    const float* __restrict__ bias, float* __restrict__ out) {
  __shared__ unsigned short As[64][40];
  __shared__ unsigned short Bs[64][40];
  const int tid = threadIdx.x;
  const int lane = tid & 63;
  const int wid = tid >> 6;
  const int wr = wid >> 1;
  const int wc = wid & 1;
  const int mbase = blockIdx.y * 64;
  const int nbase = blockIdx.x * 64;
  const int srow = tid >> 2;  // staging row 0..63
  const int skq = tid & 3;    // staging k-octet

  f32x4 acc00 = {0.f, 0.f, 0.f, 0.f};
  f32x4 acc01 = {0.f, 0.f, 0.f, 0.f};
  f32x4 acc10 = {0.f, 0.f, 0.f, 0.f};
  f32x4 acc11 = {0.f, 0.f, 0.f, 0.f};

  const int lrow = lane & 15;
  const int lk = (lane >> 4) * 8;

  for (int kb = 0; kb < 512; kb += 32) {
    __syncthreads();
    *(bf16x8*)&As[srow][skq * 8] =
        *(const bf16x8*)&A[(size_t)(mbase + srow) * 512 + kb + skq * 8];
    const float* wp = &W[(size_t)(nbase + srow) * 512 + kb + skq * 8];
    float4 w0 = *(const float4*)wp;
    float4 w1 = *(const float4*)(wp + 4);
    bf16x8 bv;
    bv[0] = (short)f2bf(w0.x); bv[1] = (short)f2bf(w0.y);
    bv[2] = (short)f2bf(w0.z); bv[3] = (short)f2bf(w0.w);
    bv[4] = (short)f2bf(w1.x); bv[5] = (short)f2bf(w1.y);
    bv[6] = (short)f2bf(w1.z); bv[7] = (short)f2bf(w1.w);
    *(bf16x8*)&Bs[srow][skq * 8] = bv;
    __syncthreads();

    bf16x8 a0 = *(const bf16x8*)&As[wr * 32 + lrow][lk];
    bf16x8 a1 = *(const bf16x8*)&As[wr * 32 + 16 + lrow][lk];
    bf16x8 b0 = *(const bf16x8*)&Bs[wc * 32 + lrow][lk];
    bf16x8 b1 = *(const bf16x8*)&Bs[wc * 32 + 16 + lrow][lk];
    acc00 = __builtin_amdgcn_mfma_f32_16x16x32_bf16(a0, b0, acc00, 0, 0, 0);
    acc01 = __builtin_amdgcn_mfma_f32_16x16x32_bf16(a0, b1, acc01, 0, 0, 0);
    acc10 = __builtin_amdgcn_mfma_f32_16x16x32_bf16(a1, b0, acc10, 0, 0, 0);
    acc11 = __builtin_amdgcn_mfma_f32_16x16x32_bf16(a1, b1, acc11, 0, 0, 0);
  }

  const int row0 = mbase + wr * 32 + (lane >> 4) * 4;
  const int col0 = nbase + wc * 32 + lrow;
#pragma unroll
  for (int ni = 0; ni < 2; ++ni) {
    int col = col0 + ni * 16;
    float bv = bias[col];
    const f32x4* a0p = (ni == 0) ? &acc00 : &acc01;
    const f32x4* a1p = (ni == 0) ? &acc10 : &acc11;
#pragma unroll
    for (int q = 0; q < 4; ++q) {
      float v0 = (*a0p)[q] + bv;
      out[(size_t)(row0 + q) * 256 + col] = fmaxf(v0, 0.0f);
      float v1 = (*a1p)[q] + bv;
      out[(size_t)(row0 + 16 + q) * 256 + col] = fmaxf(v1, 0.0f);
    }
  }
}

extern "C" void kernel_launch(void* const* d_in, const int* in_sizes, int n_in,
                              void* d_out, int out_size, void* d_ws, size_t ws_size,
                              hipStream_t stream) {
  // inputs: 0=h (unused), 1=positions, 2=past_positions, 3=W_emb, 4=b_emb
  const float2* pos = (const float2*)d_in[1];
  const float2* past = (const float2*)d_in[2];
  const float* W = (const float*)d_in[3];
  const float* bias = (const float*)d_in[4];
  float* out = (float*)d_out;

  char* ws = (char*)d_ws;
  float4* posvel = (float4*)ws;                       // 64 KB
  float4* sorted = (float4*)(ws + 64 * 1024);         // 64 KB
  int* cellid = (int*)(ws + 128 * 1024);              // 16 KB
  int* orig = (int*)(ws + 144 * 1024);                // 16 KB
  unsigned short* gridws = (unsigned short*)(ws + 160 * 1024);  // 4 MB

  prep_kernel<<<NP / 256, 256, 0, stream>>>(pos, past, posvel, cellid);
  sort_kernel<<<1, 256, 0, stream>>>(posvel, cellid, sorted, orig);
  pool_kernel<<<NP / IB, 512, 0, stream>>>(sorted, orig, gridws);
  dim3 g(256 / 64, NP / 64);
  gemm_kernel<<<g, 256, 0, stream>>>(gridws, W, bias, out);
}